// Round 16
// baseline (200.200 us; speedup 1.0000x reference)
//
#include <hip/hip_runtime.h>
#include <math.h>

#define BB 32
#define CC 256
#define NPIX 1024     // 32*32
#define KD 16
#define NHEADS 4
#define VDIM 64
#define RR 23
#define PADR 11
#define EPSBN 1e-5f

typedef short short8v __attribute__((ext_vector_type(8)));
typedef short short4v __attribute__((ext_vector_type(4)));
typedef float floatx4 __attribute__((ext_vector_type(4)));

__device__ __forceinline__ unsigned short f2bf(float f) {
  union { float f; unsigned u; } c; c.f = f;
  unsigned u = c.u;
  return (unsigned short)((u + 0x7FFFu + ((u >> 16) & 1u)) >> 16);
}
__device__ __forceinline__ float bf2f(unsigned short h) {
  union { unsigned u; float f; } c; c.u = ((unsigned)h) << 16;
  return c.f;
}

// raw stats layout: raw[0..63] q-sum, raw[64..127] q-sumsq,
//                   raw[128..191] v-sum, raw[192..255] v-sumsq
#define NINV (1.0f / 32768.0f)   // 1/(B*NPIX)

// -- K0: emb->bf16 A-layout + W pack + zero raw/lcG/esum ---------------------
__global__ __launch_bounds__(256) void k_prep(const float* __restrict__ emb,
    unsigned short* __restrict__ embA,
    const float* __restrict__ Wq, const float* __restrict__ Wk,
    const float* __restrict__ Wv, unsigned short* __restrict__ wA,
    float* __restrict__ raw, float* __restrict__ lcG, float* __restrict__ esum) {
  int bid = blockIdx.x;
  if (bid == 0) raw[threadIdx.x] = 0.f;   // 256 threads cover 256 slots
  if (bid < 46) {
    int l = bid * 256 + threadIdx.x;
    if (l >= 23 * 16 * 32) return;
    int dr = l >> 9, rem = l & 511;
    int m = rem >> 5, kd = rem & 31;
    unsigned short val = 0;
    if (kd < 23) val = f2bf(emb[(size_t)m * 529 + dr * 23 + kd]);
    embA[l] = val;
  } else if (bid < 190) {
    int idx = (bid - 46) * 256 + threadIdx.x;  // 0..36863
    int j = idx & 7, lane = (idx >> 3) & 63, ks = (idx >> 9) & 7, ot = idx >> 12;
    int o = ot * 16 + (lane & 15);
    int c = ks * 32 + (lane >> 4) * 8 + j;
    const float* src = (o < 64) ? (Wq + (size_t)o * CC)
                     : (o < 80) ? (Wk + (size_t)(o - 64) * CC)
                                : (Wv + (size_t)(o - 80) * CC);
    wA[idx] = f2bf(src[c]);
  } else if (bid < 318) {
    // zero lcG: B*1024 = 32768 floats over 128 blocks
    lcG[(bid - 190) * 256 + threadIdx.x] = 0.f;
  } else {
    // zero esum: B*16 = 512 floats over 2 blocks
    esum[(bid - 318) * 256 + threadIdx.x] = 0.f;
  }
}

// ---- K1: 1x1-conv MFMA GEMM, LDS-staged x-tile + BN partial-sum atomics ----
// x tile (256ch x 64px) staged as bf16 in LDS [ch][68]: 16 coalesced float4
// global loads/thread (256B runs), conflict-free b64 LDS writes; MFMA B-frags
// then read from LDS. 36KB LDS -> 4 blocks/CU = 16 waves/CU (2x old).
__global__ __launch_bounds__(256) void k_proj(const float* __restrict__ x,
    const unsigned short* __restrict__ wA,
    float* __restrict__ q_pre, float* __restrict__ k_pre, float* __restrict__ v_pre,
    float* __restrict__ raw) {
  __shared__ short xl[256 * 68];      // [ch][px(+4 pad)] bf16, 34.8 KB
  __shared__ float ssum[144], ssq[144];
  int b = blockIdx.y;
  int t = threadIdx.x;
  int s = t >> 6;                 // wave id = 16-pixel subtile
  int lane = t & 63;
  int nl = lane & 15, quad = lane >> 4;
  int pix0 = blockIdx.x * 64;
  int pix = pix0 + s * 16 + nl;

  if (t < 144) { ssum[t] = 0.f; ssq[t] = 0.f; }

  // stage: pass p covers ch p*16+(t>>4), 4 pixels (t&15)*4..+3
  {
    const float* xb = x + (size_t)b * CC * NPIX + pix0;
    int ch0 = t >> 4, c4 = (t & 15) * 4;
#pragma unroll
    for (int p = 0; p < 16; ++p) {
      int ch = p * 16 + ch0;
      float4 v4 = *(const float4*)(xb + (size_t)ch * NPIX + c4);
      short4v pk;
      pk.x = (short)f2bf(v4.x); pk.y = (short)f2bf(v4.y);
      pk.z = (short)f2bf(v4.z); pk.w = (short)f2bf(v4.w);
      *(short4v*)&xl[ch * 68 + c4] = pk;
    }
  }
  __syncthreads();

  const unsigned short* ap = wA + lane * 8;
  const short* xrow = &xl[s * 16 + nl];

  floatx4 acc[9];
#pragma unroll
  for (int i = 0; i < 9; ++i) acc[i] = (floatx4){0.f, 0.f, 0.f, 0.f};

#pragma unroll
  for (int ks = 0; ks < 8; ++ks) {
    union { short8v v; unsigned short u[8]; } bb;
#pragma unroll
    for (int j = 0; j < 8; ++j)
      bb.u[j] = (unsigned short)xrow[(ks * 32 + quad * 8 + j) * 68];
#pragma unroll
    for (int ot = 0; ot < 9; ++ot) {
      short8v af = *(const short8v*)(ap + ((ot * 8 + ks) << 9));
      acc[ot] = __builtin_amdgcn_mfma_f32_16x16x32_bf16(af, bb.v, acc[ot], 0, 0, 0);
    }
  }

#pragma unroll
  for (int ot = 0; ot < 9; ++ot) {
#pragma unroll
    for (int r = 0; r < 4; ++r) {
      int o = ot * 16 + quad * 4 + r;
      float val = acc[ot][r];
      if (o < 64)      q_pre[((size_t)b * 64 + o) * NPIX + pix] = val;
      else if (o < 80) k_pre[((size_t)b * 16 + (o - 64)) * NPIX + pix] = val;
      else             v_pre[((size_t)b * 64 + (o - 80)) * NPIX + pix] = val;
    }
  }

  // ---- BN partial sums: reduce over 16-pixel lanes, LDS, 1 global atomic/ch
#pragma unroll
  for (int ot = 0; ot < 9; ++ot) {
#pragma unroll
    for (int r = 0; r < 4; ++r) {
      int o = ot * 16 + quad * 4 + r;
      if (o >= 64 && o < 80) continue;    // k-channels have no BN
      float v1 = acc[ot][r];
      float v2 = v1 * v1;
#pragma unroll
      for (int m = 1; m < 16; m <<= 1) {
        v1 += __shfl_xor(v1, m);
        v2 += __shfl_xor(v2, m);
      }
      if (nl == 0) {
        atomicAdd(&ssum[o], v1);
        atomicAdd(&ssq[o], v2);
      }
    }
  }
  __syncthreads();
  if (t < 64) {                       // q channels
    atomicAdd(&raw[t], ssum[t]);
    atomicAdd(&raw[64 + t], ssq[t]);
  } else if (t < 128) {               // v channels (o = t+16)
    atomicAdd(&raw[64 + t], ssum[t + 16]);     // raw[128..191]
    atomicAdd(&raw[192 + (t - 64)], ssq[t + 16]);
  }
}

// ---------------- shared LDS layout for conv kernel ----------------
#define IMG_RS 68            // shorts per padded row
#define IMG_CS 3728          // shorts per copy (54*68=3672 used + 56 pad)
#define LAM_RS 1032          // lambda row stride in shorts (1024 + 8 pad)

union KMainLDS {
  short imgc[4 * IMG_CS];   // 29824 B
  short lam[16 * LAM_RS];   // 33024 B
};

__device__ __forceinline__ short8v ld_win(const short* p) {
  union { short8v s8; short4v s4[2]; } bu;
  bu.s4[0] = *(const short4v*)p;
  bu.s4[1] = *(const short4v*)(p + 4);
  return bu.s8;
}

// -------- K5a: grid (80,B). bx<64: PURE conv (inline BN-v) -> lamG.
// bx>=64: chunked lc siblings with UNNORMALIZED exp (softmax algebra moved to
// epi2: lc = (sum exp*v)/(sum exp)); also accumulate esum per (b,k).
__global__ __launch_bounds__(256, 3) void k_conv(const float* __restrict__ vn,
    const float* __restrict__ k_pre, const float* __restrict__ raw,
    const float* __restrict__ bn_v_w, const float* __restrict__ bn_v_b,
    const unsigned short* __restrict__ embA,
    unsigned short* __restrict__ lamG, float* __restrict__ lcG,
    float* __restrict__ esum) {
  __shared__ __align__(16) KMainLDS u;
  int b = blockIdx.y, bx = blockIdx.x, t = threadIdx.x;
  int lane = t & 63, wv = t >> 6;

  if (bx >= 64) {
    // ---------- chunked lc block: nc = bx-64 ----------
    int nc = bx - 64, n0 = nc * 64;
    float* pl = (float*)u.imgc;          // [16][64]  4 KB (exp, unnormalized)
    float* vl = pl + 16 * 64;            // [64][65]  16.6 KB
    float* vscb = vl + 64 * 65;          // [64]
    float* vshb = vscb + 64;             // [64]
    if (t < 64) {
      float mean = raw[128 + t] * NINV;
      float var = raw[192 + t] * NINV - mean * mean;
      float sc = rsqrtf(var + EPSBN) * bn_v_w[t];
      vscb[t] = sc;
      vshb[t] = bn_v_b[t] - mean * sc;
    }
    for (int l = t; l < 1024; l += 256) {
      int k = l >> 6, nn = l & 63;
      pl[l] = __expf(k_pre[((size_t)b * 16 + k) * NPIX + n0 + nn]);
    }
    __syncthreads();
    // per-chunk exp-sum partials -> global esum atomics
    {
      int k = t >> 4, j = t & 15;
      const float* pk = &pl[k * 64 + j * 4];
      float s = pk[0] + pk[1] + pk[2] + pk[3];
#pragma unroll
      for (int m = 1; m < 16; m <<= 1) s += __shfl_xor(s, m);
      if (j == 0) atomicAdd(&esum[b * 16 + k], s);
    }
    for (int l = t; l < 4096; l += 256) {
      int v64 = l >> 6, nn = l & 63;
      vl[v64 * 65 + nn] = fmaf(vn[((size_t)b * 64 + v64) * NPIX + n0 + nn],
                               vscb[v64], vshb[v64]);
    }
    __syncthreads();
    int k = t >> 4, v4 = (t & 15) * 4;
    float a0 = 0.f, a1 = 0.f, a2 = 0.f, a3 = 0.f;
    const float* pk = &pl[k * 64];
#pragma unroll 8
    for (int i = 0; i < 64; ++i) {
      float pv = pk[i];
      a0 = fmaf(pv, vl[(v4 + 0) * 65 + i], a0);
      a1 = fmaf(pv, vl[(v4 + 1) * 65 + i], a1);
      a2 = fmaf(pv, vl[(v4 + 2) * 65 + i], a2);
      a3 = fmaf(pv, vl[(v4 + 3) * 65 + i], a3);
    }
    float* dst = lcG + (size_t)b * 1024 + k * 64 + v4;
    atomicAdd(dst + 0, a0); atomicAdd(dst + 1, a1);
    atomicAdd(dst + 2, a2); atomicAdd(dst + 3, a3);
    return;
  }

  // ---------- pure conv block: v = bx ----------
  int v = bx;
  int4* z4 = (int4*)u.imgc;
  for (int l = t; l < 1864; l += 256) z4[l] = make_int4(0, 0, 0, 0);
  // BN affine for this v-channel (uniform across block)
  float vmean = raw[128 + v] * NINV;
  float vvar = raw[192 + v] * NINV - vmean * vmean;
  float vsc = rsqrtf(vvar + EPSBN) * bn_v_w[v];
  float vsh = bn_v_b[v] - vmean * vsc;
  __syncthreads();

  const float* vsrc = vn + ((size_t)b * 64 + v) * NPIX;
  for (int l = t; l < 512; l += 256) {
    int pix = l * 2;
    int y = pix >> 5, xx = pix & 31;
    float2 vv = *(const float2*)(vsrc + pix);
    unsigned short h0 = f2bf(fmaf(vv.x, vsc, vsh));
    unsigned short h1 = f2bf(fmaf(vv.y, vsc, vsh));
#pragma unroll
    for (int s = 0; s < 4; ++s) {
      int base = s * IMG_CS + (y + PADR) * IMG_RS + xx + PADR + s;
      u.imgc[base] = (short)h0;
      u.imgc[base + 1] = (short)h1;
    }
  }
  __syncthreads();

  int nl = lane & 15, quad = lane >> 4;
  int y0 = wv * 8;
  int scopy = (4 - (nl & 3)) & 3;
  int colbase = scopy * IMG_CS + nl + quad * 8 + scopy;
  const unsigned short* aptr = embA + nl * 32 + quad * 8;

  floatx4 acc[16];
#pragma unroll
  for (int i = 0; i < 16; ++i) acc[i] = (floatx4){0.f, 0.f, 0.f, 0.f};

  // prologue: cache rows y0..y0+7 (slot = row & 7)
  short8v bfrag[8][2];
#pragma unroll
  for (int rr = 0; rr < 8; ++rr) {
    const short* rp = &u.imgc[(y0 + rr) * IMG_RS + colbase];
    bfrag[rr][0] = ld_win(rp);
    bfrag[rr][1] = ld_win(rp + 16);
  }

  // depth-2 embA prefetch ring
  short8v a0 = *(const short8v*)aptr;
  short8v a1 = *(const short8v*)(aptr + 512);
#pragma unroll
  for (int dr = 0; dr < RR; ++dr) {
    short8v afrag = a0;
    a0 = a1;
    if (dr < RR - 2) a1 = *(const short8v*)(aptr + (dr + 2) * 512);
#pragma unroll
    for (int rr = 0; rr < 8; ++rr) {
      int slot = (dr + rr) & 7;
      acc[rr * 2 + 0] = __builtin_amdgcn_mfma_f32_16x16x32_bf16(afrag, bfrag[slot][0], acc[rr * 2 + 0], 0, 0, 0);
      acc[rr * 2 + 1] = __builtin_amdgcn_mfma_f32_16x16x32_bf16(afrag, bfrag[slot][1], acc[rr * 2 + 1], 0, 0, 0);
    }
    if (dr < RR - 1) {
      const short* rp = &u.imgc[(y0 + dr + 8) * IMG_RS + colbase];
      int slot = dr & 7;
      bfrag[slot][0] = ld_win(rp);
      bfrag[slot][1] = ld_win(rp + 16);
    }
  }

  __syncthreads();
#pragma unroll
  for (int tt = 0; tt < 16; ++tt) {
    int y = y0 + (tt >> 1), c0 = (tt & 1) << 4;
    int pix = y * 32 + c0 + nl;
#pragma unroll
    for (int r = 0; r < 4; ++r)
      u.lam[(quad * 4 + r) * LAM_RS + pix] = (short)f2bf(acc[tt][r]);
  }
  __syncthreads();

  // coalesced LDS -> global copy of lambda (16 rows x 1024 bf16 = 2048 uint4)
  uint4* dst = (uint4*)(lamG + ((size_t)(b * 64 + v)) * 16 * 1024);
  for (int idx = t; idx < 2048; idx += 256) {
    int row = idx >> 7, col = idx & 127;
    dst[row * 128 + col] = *(const uint4*)&u.lam[row * LAM_RS + col * 8];
  }
}

// ------ K5b: chunk-grid epilogue, z=4, inline q-stats + normalized lc -------
__global__ __launch_bounds__(256) void k_epi2(const unsigned short* __restrict__ lamG,
    const float* __restrict__ q_pre, const float* __restrict__ raw,
    const float* __restrict__ bn_q_w, const float* __restrict__ bn_q_b,
    const float* __restrict__ lcG, const float* __restrict__ esum,
    const float* __restrict__ gamma, float* __restrict__ out) {
  __shared__ float qs[64 * 64];   // [o][n] 16 KB
  __shared__ float lcs[1024];     // [k][v] 4 KB
  __shared__ float qsc[64], qsh[64], rkv[16];
  int b = blockIdx.y, nc = blockIdx.x, z = blockIdx.z, t = threadIdx.x;
  if (t < 64) {
    float mean = raw[t] * NINV;
    float var = raw[64 + t] * NINV - mean * mean;
    float sc = rsqrtf(var + EPSBN) * bn_q_w[t];
    qsc[t] = sc;
    qsh[t] = bn_q_b[t] - mean * sc;
  }
  if (t < 16) rkv[t] = 1.0f / esum[b * 16 + t];
  __syncthreads();
  for (int l = t; l < 1024; l += 256) lcs[l] = lcG[(size_t)b * 1024 + l] * rkv[l >> 6];
  int n0 = nc * 64;
  for (int l = t; l < 4096; l += 256) {
    int o = l >> 6, nn = l & 63;
    qs[l] = fmaf(q_pre[((size_t)b * 64 + o) * NPIX + n0 + nn], qsc[o], qsh[o]);
  }
  __syncthreads();
  float g1 = 1.0f + gamma[0];
  int p0 = (t & 15) * 4;
  int v = z * 16 + (t >> 4);      // 1 v per thread, z covers 16 v
  const unsigned short* ls = lamG + ((size_t)(b * 64 + v)) * 16 * 1024 + n0 + p0;
  float yacc[4][4];
#pragma unroll
  for (int h = 0; h < 4; ++h)
#pragma unroll
    for (int i = 0; i < 4; ++i) yacc[h][i] = 0.f;
#pragma unroll
  for (int k = 0; k < 16; ++k) {
    uint2 w = *(const uint2*)(ls + k * 1024);
    float lv = lcs[k * 64 + v];
    float l0 = bf2f((unsigned short)(w.x & 0xffffu)) + lv;
    float l1 = bf2f((unsigned short)(w.x >> 16)) + lv;
    float l2 = bf2f((unsigned short)(w.y & 0xffffu)) + lv;
    float l3 = bf2f((unsigned short)(w.y >> 16)) + lv;
#pragma unroll
    for (int h = 0; h < 4; ++h) {
      const float* qrow = &qs[(h * 16 + k) * 64 + p0];
      yacc[h][0] = fmaf(qrow[0], l0, yacc[h][0]);
      yacc[h][1] = fmaf(qrow[1], l1, yacc[h][1]);
      yacc[h][2] = fmaf(qrow[2], l2, yacc[h][2]);
      yacc[h][3] = fmaf(qrow[3], l3, yacc[h][3]);
    }
  }
#pragma unroll
  for (int h = 0; h < 4; ++h) {
    float4 r;
    r.x = g1 * yacc[h][0]; r.y = g1 * yacc[h][1];
    r.z = g1 * yacc[h][2]; r.w = g1 * yacc[h][3];
    *(float4*)&out[((size_t)b * 256 + h * 64 + v) * NPIX + n0 + p0] = r;
  }
}

// ======== Fallback chain (proven R10/R12 kernels, used only if ws small) ====
__global__ __launch_bounds__(256) void k_nvsm(float* __restrict__ vn,
    const float* __restrict__ raw,
    const float* __restrict__ bn_v_w, const float* __restrict__ bn_v_b,
    const float* __restrict__ k_pre, float* __restrict__ p) {
  __shared__ float vsc[64], vsh[64];
  __shared__ float shm[4], shs[4];
  int b = blockIdx.y, bx = blockIdx.x, t = threadIdx.x;
  if (bx < 16) {
    if (t < 64) {
      float mean = raw[128 + t] * NINV;
      float var = raw[192 + t] * NINV - mean * mean;
      float sc = rsqrtf(var + EPSBN) * bn_v_w[t];
      vsc[t] = sc;
      vsh[t] = bn_v_b[t] - mean * sc;
    }
    __syncthreads();
    int n0 = bx * 64;
    for (int l = t; l < 4096; l += 256) {
      int o = l >> 6, nn = l & 63;
      size_t a = ((size_t)b * 64 + o) * NPIX + n0 + nn;
      vn[a] = fmaf(vn[a], vsc[o], vsh[o]);
    }
  } else {
    int k = bx - 16;
    const float* src = k_pre + ((size_t)b * 16 + k) * NPIX;
    float v[4];
    float mx = -1e30f;
#pragma unroll
    for (int i = 0; i < 4; ++i) { v[i] = src[t + 256 * i]; mx = fmaxf(mx, v[i]); }
#pragma unroll
    for (int off = 32; off > 0; off >>= 1) mx = fmaxf(mx, __shfl_down(mx, off));
    if ((t & 63) == 0) shm[t >> 6] = mx;
    __syncthreads();
    mx = fmaxf(fmaxf(shm[0], shm[1]), fmaxf(shm[2], shm[3]));
    float s = 0.f;
#pragma unroll
    for (int i = 0; i < 4; ++i) { v[i] = __expf(v[i] - mx); s += v[i]; }
#pragma unroll
    for (int off = 32; off > 0; off >>= 1) s += __shfl_down(s, off);
    if ((t & 63) == 0) shs[t >> 6] = s;
    __syncthreads();
    float r = 1.0f / (shs[0] + shs[1] + shs[2] + shs[3]);
    float* dst = p + ((size_t)b * 16 + k) * NPIX;
#pragma unroll
    for (int i = 0; i < 4; ++i) dst[t + 256 * i] = v[i] * r;
  }
}

__global__ __launch_bounds__(256, 3) void k_fused(const float* __restrict__ vn,
    const float* __restrict__ q_pre, const float* __restrict__ raw,
    const float* __restrict__ bn_q_w, const float* __restrict__ bn_q_b,
    const float* __restrict__ p, const unsigned short* __restrict__ embA,
    const float* __restrict__ gamma, float* __restrict__ out) {
  __shared__ __align__(16) KMainLDS u;
  __shared__ float lcv[16];
  __shared__ float red[256];
  __shared__ float qsc[64], qsh[64];
  int b = blockIdx.y, v = blockIdx.x, t = threadIdx.x;

  int4* z4 = (int4*)u.imgc;
  for (int l = t; l < 1864; l += 256) z4[l] = make_int4(0, 0, 0, 0);
  if (t < 64) {
    float mean = raw[t] * NINV;
    float var = raw[64 + t] * NINV - mean * mean;
    float sc = rsqrtf(var + EPSBN) * bn_q_w[t];
    qsc[t] = sc;
    qsh[t] = bn_q_b[t] - mean * sc;
  }
  {
    int kk = t & 15, ch = t >> 4;
    const float* pp = p + ((size_t)b * 16 + kk) * NPIX + ch * 64;
    const float* vv = vn + ((size_t)b * 64 + v) * NPIX + ch * 64;
    float part = 0.f;
#pragma unroll 8
    for (int i = 0; i < 64; ++i) part = fmaf(pp[i], vv[i], part);
    red[t] = part;
  }
  __syncthreads();
  if (t < 16) {
    float s = 0.f;
#pragma unroll
    for (int c = 0; c < 16; ++c) s += red[c * 16 + t];
    lcv[t] = s;
  }

  const float* vsrc = vn + ((size_t)b * 64 + v) * NPIX;
  for (int l = t; l < 512; l += 256) {
    int pix = l * 2;
    int y = pix >> 5, xx = pix & 31;
    float2 vv = *(const float2*)(vsrc + pix);
    unsigned short h0 = f2bf(vv.x), h1 = f2bf(vv.y);
#pragma unroll
    for (int s = 0; s < 4; ++s) {
      int base = s * IMG_CS + (y + PADR) * IMG_RS + xx + PADR + s;
      u.imgc[base] = (short)h0;
      u.imgc[base + 1] = (short)h1;
    }
  }
  __syncthreads();

  int lane = t & 63, wv = t >> 6;
  int nl = lane & 15, quad = lane >> 4;
  int y0 = wv * 8;
  int scopy = (4 - (nl & 3)) & 3;
  int colbase = scopy * IMG_CS + nl + quad * 8 + scopy;
  const unsigned short* aptr = embA + nl * 32 + quad * 8;

  floatx4 acc[16];
#pragma unroll
  for (int i = 0; i < 16; ++i) acc[i] = (floatx4){0.f, 0.f, 0.f, 0.f};

  short8v bfrag[8][2];
#pragma unroll
  for (int rr = 0; rr < 8; ++rr) {
    const short* rp = &u.imgc[(y0 + rr) * IMG_RS + colbase];
    bfrag[rr][0] = ld_win(rp);
    bfrag[rr][1] = ld_win(rp + 16);
  }

  short8v a0 = *(const short8v*)aptr;
  short8v a1 = *(const short8v*)(aptr + 512);
#pragma unroll
  for (int dr = 0; dr < RR; ++dr) {
    short8v afrag = a0;
    a0 = a1;
    if (dr < RR - 2) a1 = *(const short8v*)(aptr + (dr + 2) * 512);
#pragma unroll
    for (int rr = 0; rr < 8; ++rr) {
      int slot = (dr + rr) & 7;
      acc[rr * 2 + 0] = __builtin_amdgcn_mfma_f32_16x16x32_bf16(afrag, bfrag[slot][0], acc[rr * 2 + 0], 0, 0, 0);
      acc[rr * 2 + 1] = __builtin_amdgcn_mfma_f32_16x16x32_bf16(afrag, bfrag[slot][1], acc[rr * 2 + 1], 0, 0, 0);
    }
    if (dr < RR - 1) {
      const short* rp = &u.imgc[(y0 + dr + 8) * IMG_RS + colbase];
      int slot = dr & 7;
      bfrag[slot][0] = ld_win(rp);
      bfrag[slot][1] = ld_win(rp + 16);
    }
  }

  __syncthreads();
#pragma unroll
  for (int tt = 0; tt < 16; ++tt) {
    int y = y0 + (tt >> 1), c0 = (tt & 1) << 4;
    int pix = y * 32 + c0 + nl;
#pragma unroll
    for (int r = 0; r < 4; ++r)
      u.lam[(quad * 4 + r) * LAM_RS + pix] = (short)f2bf(acc[tt][r] + lcv[quad * 4 + r]);
  }
  __syncthreads();

  int p0 = t * 4;
  float yacc[4][4];
#pragma unroll
  for (int h = 0; h < 4; ++h)
#pragma unroll
    for (int i = 0; i < 4; ++i) yacc[h][i] = 0.f;
  const float* qb = q_pre + ((size_t)b * 64) * NPIX + p0;
#pragma unroll
  for (int k = 0; k < 16; ++k) {
    uint2 w = *(const uint2*)&u.lam[k * LAM_RS + p0];
    float l0 = bf2f((unsigned short)(w.x & 0xffffu));
    float l1 = bf2f((unsigned short)(w.x >> 16));
    float l2 = bf2f((unsigned short)(w.y & 0xffffu));
    float l3 = bf2f((unsigned short)(w.y >> 16));
#pragma unroll
    for (int h = 0; h < 4; ++h) {
      int o = h * 16 + k;
      float4 qv = *(const float4*)(qb + (size_t)o * NPIX);
      yacc[h][0] = fmaf(fmaf(qv.x, qsc[o], qsh[o]), l0, yacc[h][0]);
      yacc[h][1] = fmaf(fmaf(qv.y, qsc[o], qsh[o]), l1, yacc[h][1]);
      yacc[h][2] = fmaf(fmaf(qv.z, qsc[o], qsh[o]), l2, yacc[h][2]);
      yacc[h][3] = fmaf(fmaf(qv.w, qsc[o], qsh[o]), l3, yacc[h][3]);
    }
  }
  float g1 = 1.0f + gamma[0];
#pragma unroll
  for (int h = 0; h < 4; ++h) {
    float4 r;
    r.x = g1 * yacc[h][0]; r.y = g1 * yacc[h][1];
    r.z = g1 * yacc[h][2]; r.w = g1 * yacc[h][3];
    *(float4*)&out[((size_t)b * 256 + h * 64 + v) * NPIX + p0] = r;
  }
}

extern "C" void kernel_launch(void* const* d_in, const int* in_sizes, int n_in,
                              void* d_out, int out_size, void* d_ws, size_t ws_size,
                              hipStream_t stream) {
  const float* x      = (const float*)d_in[0];
  const float* Wq     = (const float*)d_in[1];
  const float* bn_q_w = (const float*)d_in[2];
  const float* bn_q_b = (const float*)d_in[3];
  const float* Wk     = (const float*)d_in[4];
  const float* Wv     = (const float*)d_in[5];
  const float* bn_v_w = (const float*)d_in[6];
  const float* bn_v_b = (const float*)d_in[7];
  const float* emb    = (const float*)d_in[8];
  const float* gamma  = (const float*)d_in[9];
  float* out = (float*)d_out;

  float* ws    = (float*)d_ws;
  float* q_pre = ws;                                     // B*64*N
  float* k_pre = q_pre + (size_t)BB * 64 * NPIX;         // B*16*N
  float* vn    = k_pre + (size_t)BB * 16 * NPIX;         // B*64*N (raw)
  float* p     = vn    + (size_t)BB * 64 * NPIX;         // B*16*N (fallback only)
  float* raw   = p     + (size_t)BB * 16 * NPIX;         // 256 raw BN sums
  float* lcG   = raw + 256;                              // B*16*64 lambda_c (unnorm)
  float* esum  = lcG + (size_t)BB * 1024;                // B*16 exp sums
  unsigned short* embA = (unsigned short*)(esum + BB * 32);
  unsigned short* wA   = embA + 23 * 16 * 32;            // 144*256 ushorts
  unsigned short* lamG = wA + 144 * 256;                 // B*64*16*N ushorts (64 MB)

  size_t need = ((size_t)(lamG - (unsigned short*)ws)) * 2
              + (size_t)BB * 64 * 16 * NPIX * 2;

  k_prep  <<<dim3(320),       256, 0, stream>>>(emb, embA, Wq, Wk, Wv, wA, raw, lcG, esum);
  k_proj  <<<dim3(16, BB),    256, 0, stream>>>(x, wA, q_pre, k_pre, vn, raw);
  if (ws_size >= need) {
    k_conv<<<dim3(80, BB),    256, 0, stream>>>(vn, k_pre, raw, bn_v_w, bn_v_b, embA, lamG, lcG, esum);
    k_epi2<<<dim3(16, BB, 4), 256, 0, stream>>>(lamG, q_pre, raw, bn_q_w, bn_q_b, lcG, esum, gamma, out);
  } else {
    k_nvsm<<<dim3(32, BB),    256, 0, stream>>>(vn, raw, bn_v_w, bn_v_b, k_pre, p);
    k_fused<<<dim3(64, BB),   256, 0, stream>>>(vn, q_pre, raw, bn_q_w, bn_q_b, p, embA, gamma, out);
  }
}

// Round 17
// 184.095 us; speedup vs baseline: 1.0875x; 1.0875x over previous
//
#include <hip/hip_runtime.h>
#include <math.h>

#define BB 32
#define CC 256
#define NPIX 1024     // 32*32
#define KD 16
#define NHEADS 4
#define VDIM 64
#define RR 23
#define PADR 11
#define EPSBN 1e-5f

typedef short short8v __attribute__((ext_vector_type(8)));
typedef short short4v __attribute__((ext_vector_type(4)));
typedef float floatx4 __attribute__((ext_vector_type(4)));

__device__ __forceinline__ unsigned short f2bf(float f) {
  union { float f; unsigned u; } c; c.f = f;
  unsigned u = c.u;
  return (unsigned short)((u + 0x7FFFu + ((u >> 16) & 1u)) >> 16);
}
__device__ __forceinline__ float bf2f(unsigned short h) {
  union { unsigned u; float f; } c; c.u = ((unsigned)h) << 16;
  return c.f;
}

// raw stats layout: raw[0..63] q-sum, raw[64..127] q-sumsq,
//                   raw[128..191] v-sum, raw[192..255] v-sumsq
#define NINV (1.0f / 32768.0f)   // 1/(B*NPIX)

// -- K0: emb->bf16 A-layout + W pack + zero raw/lcG/esum ---------------------
__global__ __launch_bounds__(256) void k_prep(const float* __restrict__ emb,
    unsigned short* __restrict__ embA,
    const float* __restrict__ Wq, const float* __restrict__ Wk,
    const float* __restrict__ Wv, unsigned short* __restrict__ wA,
    float* __restrict__ raw, float* __restrict__ lcG, float* __restrict__ esum) {
  int bid = blockIdx.x;
  if (bid == 0) raw[threadIdx.x] = 0.f;   // 256 threads cover 256 slots
  if (bid < 46) {
    int l = bid * 256 + threadIdx.x;
    if (l >= 23 * 16 * 32) return;
    int dr = l >> 9, rem = l & 511;
    int m = rem >> 5, kd = rem & 31;
    unsigned short val = 0;
    if (kd < 23) val = f2bf(emb[(size_t)m * 529 + dr * 23 + kd]);
    embA[l] = val;
  } else if (bid < 190) {
    int idx = (bid - 46) * 256 + threadIdx.x;  // 0..36863
    int j = idx & 7, lane = (idx >> 3) & 63, ks = (idx >> 9) & 7, ot = idx >> 12;
    int o = ot * 16 + (lane & 15);
    int c = ks * 32 + (lane >> 4) * 8 + j;
    const float* src = (o < 64) ? (Wq + (size_t)o * CC)
                     : (o < 80) ? (Wk + (size_t)(o - 64) * CC)
                                : (Wv + (size_t)(o - 80) * CC);
    wA[idx] = f2bf(src[c]);
  } else if (bid < 318) {
    // zero lcG: B*1024 = 32768 floats over 128 blocks
    lcG[(bid - 190) * 256 + threadIdx.x] = 0.f;
  } else {
    // zero esum: B*16 = 512 floats over 2 blocks
    esum[(bid - 318) * 256 + threadIdx.x] = 0.f;
  }
}

// ---------------- K1: 1x1-conv MFMA GEMM + BN partial-sum atomics -----------
// (R14-verbatim direct-global version: R15's LDS-staged variant regressed
// +13us -- 64 scalar ds_read_u16 fragment reads serialize; direct global
// loads pipeline against MFMAs without a barrier.)
__global__ __launch_bounds__(256) void k_proj(const float* __restrict__ x,
    const unsigned short* __restrict__ wA,
    float* __restrict__ q_pre, float* __restrict__ k_pre, float* __restrict__ v_pre,
    float* __restrict__ raw) {
  __shared__ float ssum[144], ssq[144];
  int b = blockIdx.y;
  int t = threadIdx.x;
  int s = t >> 6;                 // wave id = 16-pixel subtile
  int lane = t & 63;
  int nl = lane & 15, quad = lane >> 4;
  int pix = blockIdx.x * 64 + s * 16 + nl;

  if (t < 144) { ssum[t] = 0.f; ssq[t] = 0.f; }
  __syncthreads();

  const float* xb = x + ((size_t)b * CC) * NPIX + pix;
  const unsigned short* ap = wA + lane * 8;

  floatx4 acc[9];
#pragma unroll
  for (int i = 0; i < 9; ++i) acc[i] = (floatx4){0.f, 0.f, 0.f, 0.f};

#pragma unroll
  for (int ks = 0; ks < 8; ++ks) {
    union { short8v v; unsigned short u[8]; } bb;
    const float* xc = xb + ((size_t)(ks * 32 + quad * 8)) * NPIX;
#pragma unroll
    for (int j = 0; j < 8; ++j) bb.u[j] = f2bf(xc[(size_t)j * NPIX]);
#pragma unroll
    for (int ot = 0; ot < 9; ++ot) {
      short8v af = *(const short8v*)(ap + ((ot * 8 + ks) << 9));
      acc[ot] = __builtin_amdgcn_mfma_f32_16x16x32_bf16(af, bb.v, acc[ot], 0, 0, 0);
    }
  }

#pragma unroll
  for (int ot = 0; ot < 9; ++ot) {
#pragma unroll
    for (int r = 0; r < 4; ++r) {
      int o = ot * 16 + quad * 4 + r;
      float val = acc[ot][r];
      if (o < 64)      q_pre[((size_t)b * 64 + o) * NPIX + pix] = val;
      else if (o < 80) k_pre[((size_t)b * 16 + (o - 64)) * NPIX + pix] = val;
      else             v_pre[((size_t)b * 64 + (o - 80)) * NPIX + pix] = val;
    }
  }

  // ---- BN partial sums: reduce over 16-pixel lanes, LDS, 1 global atomic/ch
#pragma unroll
  for (int ot = 0; ot < 9; ++ot) {
#pragma unroll
    for (int r = 0; r < 4; ++r) {
      int o = ot * 16 + quad * 4 + r;
      if (o >= 64 && o < 80) continue;    // k-channels have no BN
      float v1 = acc[ot][r];
      float v2 = v1 * v1;
#pragma unroll
      for (int m = 1; m < 16; m <<= 1) {
        v1 += __shfl_xor(v1, m);
        v2 += __shfl_xor(v2, m);
      }
      if (nl == 0) {
        atomicAdd(&ssum[o], v1);
        atomicAdd(&ssq[o], v2);
      }
    }
  }
  __syncthreads();
  if (t < 64) {                       // q channels
    atomicAdd(&raw[t], ssum[t]);
    atomicAdd(&raw[64 + t], ssq[t]);
  } else if (t < 128) {               // v channels (o = t+16)
    atomicAdd(&raw[64 + t], ssum[t + 16]);     // raw[128..191]
    atomicAdd(&raw[192 + (t - 64)], ssq[t + 16]);
  }
}

// ---------------- shared LDS layout for conv kernel ----------------
#define IMG_RS 68            // shorts per padded row
#define IMG_CS 3728          // shorts per copy (54*68=3672 used + 56 pad)
#define LAM_RS 1032          // lambda row stride in shorts (1024 + 8 pad)

union KMainLDS {
  short imgc[4 * IMG_CS];   // 29824 B
  short lam[16 * LAM_RS];   // 33024 B
};

__device__ __forceinline__ short8v ld_win(const short* p) {
  union { short8v s8; short4v s4[2]; } bu;
  bu.s4[0] = *(const short4v*)p;
  bu.s4[1] = *(const short4v*)(p + 4);
  return bu.s8;
}

// -------- K5a: grid (80,B). bx<64: PURE conv (inline BN-v) -> lamG.
// bx>=64: chunked lc siblings with UNNORMALIZED exp (softmax algebra moved to
// epi2: lc = (sum exp*v)/(sum exp)); also accumulate esum per (b,k).
__global__ __launch_bounds__(256, 3) void k_conv(const float* __restrict__ vn,
    const float* __restrict__ k_pre, const float* __restrict__ raw,
    const float* __restrict__ bn_v_w, const float* __restrict__ bn_v_b,
    const unsigned short* __restrict__ embA,
    unsigned short* __restrict__ lamG, float* __restrict__ lcG,
    float* __restrict__ esum) {
  __shared__ __align__(16) KMainLDS u;
  int b = blockIdx.y, bx = blockIdx.x, t = threadIdx.x;
  int lane = t & 63, wv = t >> 6;

  if (bx >= 64) {
    // ---------- chunked lc block: nc = bx-64 ----------
    int nc = bx - 64, n0 = nc * 64;
    float* pl = (float*)u.imgc;          // [16][64]  4 KB (exp, unnormalized)
    float* vl = pl + 16 * 64;            // [64][65]  16.6 KB
    float* vscb = vl + 64 * 65;          // [64]
    float* vshb = vscb + 64;             // [64]
    if (t < 64) {
      float mean = raw[128 + t] * NINV;
      float var = raw[192 + t] * NINV - mean * mean;
      float sc = rsqrtf(var + EPSBN) * bn_v_w[t];
      vscb[t] = sc;
      vshb[t] = bn_v_b[t] - mean * sc;
    }
    for (int l = t; l < 1024; l += 256) {
      int k = l >> 6, nn = l & 63;
      pl[l] = __expf(k_pre[((size_t)b * 16 + k) * NPIX + n0 + nn]);
    }
    __syncthreads();
    // per-chunk exp-sum partials -> global esum atomics
    {
      int k = t >> 4, j = t & 15;
      const float* pk = &pl[k * 64 + j * 4];
      float s = pk[0] + pk[1] + pk[2] + pk[3];
#pragma unroll
      for (int m = 1; m < 16; m <<= 1) s += __shfl_xor(s, m);
      if (j == 0) atomicAdd(&esum[b * 16 + k], s);
    }
    for (int l = t; l < 4096; l += 256) {
      int v64 = l >> 6, nn = l & 63;
      vl[v64 * 65 + nn] = fmaf(vn[((size_t)b * 64 + v64) * NPIX + n0 + nn],
                               vscb[v64], vshb[v64]);
    }
    __syncthreads();
    int k = t >> 4, v4 = (t & 15) * 4;
    float a0 = 0.f, a1 = 0.f, a2 = 0.f, a3 = 0.f;
    const float* pk = &pl[k * 64];
#pragma unroll 8
    for (int i = 0; i < 64; ++i) {
      float pv = pk[i];
      a0 = fmaf(pv, vl[(v4 + 0) * 65 + i], a0);
      a1 = fmaf(pv, vl[(v4 + 1) * 65 + i], a1);
      a2 = fmaf(pv, vl[(v4 + 2) * 65 + i], a2);
      a3 = fmaf(pv, vl[(v4 + 3) * 65 + i], a3);
    }
    float* dst = lcG + (size_t)b * 1024 + k * 64 + v4;
    atomicAdd(dst + 0, a0); atomicAdd(dst + 1, a1);
    atomicAdd(dst + 2, a2); atomicAdd(dst + 3, a3);
    return;
  }

  // ---------- pure conv block: v = bx ----------
  int v = bx;
  int4* z4 = (int4*)u.imgc;
  for (int l = t; l < 1864; l += 256) z4[l] = make_int4(0, 0, 0, 0);
  // BN affine for this v-channel (uniform across block)
  float vmean = raw[128 + v] * NINV;
  float vvar = raw[192 + v] * NINV - vmean * vmean;
  float vsc = rsqrtf(vvar + EPSBN) * bn_v_w[v];
  float vsh = bn_v_b[v] - vmean * vsc;
  __syncthreads();

  const float* vsrc = vn + ((size_t)b * 64 + v) * NPIX;
  for (int l = t; l < 512; l += 256) {
    int pix = l * 2;
    int y = pix >> 5, xx = pix & 31;
    float2 vv = *(const float2*)(vsrc + pix);
    unsigned short h0 = f2bf(fmaf(vv.x, vsc, vsh));
    unsigned short h1 = f2bf(fmaf(vv.y, vsc, vsh));
#pragma unroll
    for (int s = 0; s < 4; ++s) {
      int base = s * IMG_CS + (y + PADR) * IMG_RS + xx + PADR + s;
      u.imgc[base] = (short)h0;
      u.imgc[base + 1] = (short)h1;
    }
  }
  __syncthreads();

  int nl = lane & 15, quad = lane >> 4;
  int y0 = wv * 8;
  int scopy = (4 - (nl & 3)) & 3;
  int colbase = scopy * IMG_CS + nl + quad * 8 + scopy;
  const unsigned short* aptr = embA + nl * 32 + quad * 8;

  floatx4 acc[16];
#pragma unroll
  for (int i = 0; i < 16; ++i) acc[i] = (floatx4){0.f, 0.f, 0.f, 0.f};

  // prologue: cache rows y0..y0+7 (slot = row & 7)
  short8v bfrag[8][2];
#pragma unroll
  for (int rr = 0; rr < 8; ++rr) {
    const short* rp = &u.imgc[(y0 + rr) * IMG_RS + colbase];
    bfrag[rr][0] = ld_win(rp);
    bfrag[rr][1] = ld_win(rp + 16);
  }

  // depth-2 embA prefetch ring
  short8v a0 = *(const short8v*)aptr;
  short8v a1 = *(const short8v*)(aptr + 512);
#pragma unroll
  for (int dr = 0; dr < RR; ++dr) {
    short8v afrag = a0;
    a0 = a1;
    if (dr < RR - 2) a1 = *(const short8v*)(aptr + (dr + 2) * 512);
#pragma unroll
    for (int rr = 0; rr < 8; ++rr) {
      int slot = (dr + rr) & 7;
      acc[rr * 2 + 0] = __builtin_amdgcn_mfma_f32_16x16x32_bf16(afrag, bfrag[slot][0], acc[rr * 2 + 0], 0, 0, 0);
      acc[rr * 2 + 1] = __builtin_amdgcn_mfma_f32_16x16x32_bf16(afrag, bfrag[slot][1], acc[rr * 2 + 1], 0, 0, 0);
    }
    if (dr < RR - 1) {
      const short* rp = &u.imgc[(y0 + dr + 8) * IMG_RS + colbase];
      int slot = dr & 7;
      bfrag[slot][0] = ld_win(rp);
      bfrag[slot][1] = ld_win(rp + 16);
    }
  }

  __syncthreads();
#pragma unroll
  for (int tt = 0; tt < 16; ++tt) {
    int y = y0 + (tt >> 1), c0 = (tt & 1) << 4;
    int pix = y * 32 + c0 + nl;
#pragma unroll
    for (int r = 0; r < 4; ++r)
      u.lam[(quad * 4 + r) * LAM_RS + pix] = (short)f2bf(acc[tt][r]);
  }
  __syncthreads();

  // coalesced LDS -> global copy of lambda (16 rows x 1024 bf16 = 2048 uint4)
  uint4* dst = (uint4*)(lamG + ((size_t)(b * 64 + v)) * 16 * 1024);
  for (int idx = t; idx < 2048; idx += 256) {
    int row = idx >> 7, col = idx & 127;
    dst[row * 128 + col] = *(const uint4*)&u.lam[row * LAM_RS + col * 8];
  }
}

// ------ K5b: chunk-grid epilogue, z=4, inline q-stats + normalized lc -------
__global__ __launch_bounds__(256) void k_epi2(const unsigned short* __restrict__ lamG,
    const float* __restrict__ q_pre, const float* __restrict__ raw,
    const float* __restrict__ bn_q_w, const float* __restrict__ bn_q_b,
    const float* __restrict__ lcG, const float* __restrict__ esum,
    const float* __restrict__ gamma, float* __restrict__ out) {
  __shared__ float qs[64 * 64];   // [o][n] 16 KB
  __shared__ float lcs[1024];     // [k][v] 4 KB
  __shared__ float qsc[64], qsh[64], rkv[16];
  int b = blockIdx.y, nc = blockIdx.x, z = blockIdx.z, t = threadIdx.x;
  if (t < 64) {
    float mean = raw[t] * NINV;
    float var = raw[64 + t] * NINV - mean * mean;
    float sc = rsqrtf(var + EPSBN) * bn_q_w[t];
    qsc[t] = sc;
    qsh[t] = bn_q_b[t] - mean * sc;
  }
  if (t < 16) rkv[t] = 1.0f / esum[b * 16 + t];
  __syncthreads();
  for (int l = t; l < 1024; l += 256) lcs[l] = lcG[(size_t)b * 1024 + l] * rkv[l >> 6];
  int n0 = nc * 64;
  for (int l = t; l < 4096; l += 256) {
    int o = l >> 6, nn = l & 63;
    qs[l] = fmaf(q_pre[((size_t)b * 64 + o) * NPIX + n0 + nn], qsc[o], qsh[o]);
  }
  __syncthreads();
  float g1 = 1.0f + gamma[0];
  int p0 = (t & 15) * 4;
  int v = z * 16 + (t >> 4);      // 1 v per thread, z covers 16 v
  const unsigned short* ls = lamG + ((size_t)(b * 64 + v)) * 16 * 1024 + n0 + p0;
  float yacc[4][4];
#pragma unroll
  for (int h = 0; h < 4; ++h)
#pragma unroll
    for (int i = 0; i < 4; ++i) yacc[h][i] = 0.f;
#pragma unroll
  for (int k = 0; k < 16; ++k) {
    uint2 w = *(const uint2*)(ls + k * 1024);
    float lv = lcs[k * 64 + v];
    float l0 = bf2f((unsigned short)(w.x & 0xffffu)) + lv;
    float l1 = bf2f((unsigned short)(w.x >> 16)) + lv;
    float l2 = bf2f((unsigned short)(w.y & 0xffffu)) + lv;
    float l3 = bf2f((unsigned short)(w.y >> 16)) + lv;
#pragma unroll
    for (int h = 0; h < 4; ++h) {
      const float* qrow = &qs[(h * 16 + k) * 64 + p0];
      yacc[h][0] = fmaf(qrow[0], l0, yacc[h][0]);
      yacc[h][1] = fmaf(qrow[1], l1, yacc[h][1]);
      yacc[h][2] = fmaf(qrow[2], l2, yacc[h][2]);
      yacc[h][3] = fmaf(qrow[3], l3, yacc[h][3]);
    }
  }
#pragma unroll
  for (int h = 0; h < 4; ++h) {
    float4 r;
    r.x = g1 * yacc[h][0]; r.y = g1 * yacc[h][1];
    r.z = g1 * yacc[h][2]; r.w = g1 * yacc[h][3];
    *(float4*)&out[((size_t)b * 256 + h * 64 + v) * NPIX + n0 + p0] = r;
  }
}

// ======== Fallback chain (proven R10/R12 kernels, used only if ws small) ====
__global__ __launch_bounds__(256) void k_nvsm(float* __restrict__ vn,
    const float* __restrict__ raw,
    const float* __restrict__ bn_v_w, const float* __restrict__ bn_v_b,
    const float* __restrict__ k_pre, float* __restrict__ p) {
  __shared__ float vsc[64], vsh[64];
  __shared__ float shm[4], shs[4];
  int b = blockIdx.y, bx = blockIdx.x, t = threadIdx.x;
  if (bx < 16) {
    if (t < 64) {
      float mean = raw[128 + t] * NINV;
      float var = raw[192 + t] * NINV - mean * mean;
      float sc = rsqrtf(var + EPSBN) * bn_v_w[t];
      vsc[t] = sc;
      vsh[t] = bn_v_b[t] - mean * sc;
    }
    __syncthreads();
    int n0 = bx * 64;
    for (int l = t; l < 4096; l += 256) {
      int o = l >> 6, nn = l & 63;
      size_t a = ((size_t)b * 64 + o) * NPIX + n0 + nn;
      vn[a] = fmaf(vn[a], vsc[o], vsh[o]);
    }
  } else {
    int k = bx - 16;
    const float* src = k_pre + ((size_t)b * 16 + k) * NPIX;
    float v[4];
    float mx = -1e30f;
#pragma unroll
    for (int i = 0; i < 4; ++i) { v[i] = src[t + 256 * i]; mx = fmaxf(mx, v[i]); }
#pragma unroll
    for (int off = 32; off > 0; off >>= 1) mx = fmaxf(mx, __shfl_down(mx, off));
    if ((t & 63) == 0) shm[t >> 6] = mx;
    __syncthreads();
    mx = fmaxf(fmaxf(shm[0], shm[1]), fmaxf(shm[2], shm[3]));
    float s = 0.f;
#pragma unroll
    for (int i = 0; i < 4; ++i) { v[i] = __expf(v[i] - mx); s += v[i]; }
#pragma unroll
    for (int off = 32; off > 0; off >>= 1) s += __shfl_down(s, off);
    if ((t & 63) == 0) shs[t >> 6] = s;
    __syncthreads();
    float r = 1.0f / (shs[0] + shs[1] + shs[2] + shs[3]);
    float* dst = p + ((size_t)b * 16 + k) * NPIX;
#pragma unroll
    for (int i = 0; i < 4; ++i) dst[t + 256 * i] = v[i] * r;
  }
}

__global__ __launch_bounds__(256, 3) void k_fused(const float* __restrict__ vn,
    const float* __restrict__ q_pre, const float* __restrict__ raw,
    const float* __restrict__ bn_q_w, const float* __restrict__ bn_q_b,
    const float* __restrict__ p, const unsigned short* __restrict__ embA,
    const float* __restrict__ gamma, float* __restrict__ out) {
  __shared__ __align__(16) KMainLDS u;
  __shared__ float lcv[16];
  __shared__ float red[256];
  __shared__ float qsc[64], qsh[64];
  int b = blockIdx.y, v = blockIdx.x, t = threadIdx.x;

  int4* z4 = (int4*)u.imgc;
  for (int l = t; l < 1864; l += 256) z4[l] = make_int4(0, 0, 0, 0);
  if (t < 64) {
    float mean = raw[t] * NINV;
    float var = raw[64 + t] * NINV - mean * mean;
    float sc = rsqrtf(var + EPSBN) * bn_q_w[t];
    qsc[t] = sc;
    qsh[t] = bn_q_b[t] - mean * sc;
  }
  {
    int kk = t & 15, ch = t >> 4;
    const float* pp = p + ((size_t)b * 16 + kk) * NPIX + ch * 64;
    const float* vv = vn + ((size_t)b * 64 + v) * NPIX + ch * 64;
    float part = 0.f;
#pragma unroll 8
    for (int i = 0; i < 64; ++i) part = fmaf(pp[i], vv[i], part);
    red[t] = part;
  }
  __syncthreads();
  if (t < 16) {
    float s = 0.f;
#pragma unroll
    for (int c = 0; c < 16; ++c) s += red[c * 16 + t];
    lcv[t] = s;
  }

  const float* vsrc = vn + ((size_t)b * 64 + v) * NPIX;
  for (int l = t; l < 512; l += 256) {
    int pix = l * 2;
    int y = pix >> 5, xx = pix & 31;
    float2 vv = *(const float2*)(vsrc + pix);
    unsigned short h0 = f2bf(vv.x), h1 = f2bf(vv.y);
#pragma unroll
    for (int s = 0; s < 4; ++s) {
      int base = s * IMG_CS + (y + PADR) * IMG_RS + xx + PADR + s;
      u.imgc[base] = (short)h0;
      u.imgc[base + 1] = (short)h1;
    }
  }
  __syncthreads();

  int lane = t & 63, wv = t >> 6;
  int nl = lane & 15, quad = lane >> 4;
  int y0 = wv * 8;
  int scopy = (4 - (nl & 3)) & 3;
  int colbase = scopy * IMG_CS + nl + quad * 8 + scopy;
  const unsigned short* aptr = embA + nl * 32 + quad * 8;

  floatx4 acc[16];
#pragma unroll
  for (int i = 0; i < 16; ++i) acc[i] = (floatx4){0.f, 0.f, 0.f, 0.f};

  short8v bfrag[8][2];
#pragma unroll
  for (int rr = 0; rr < 8; ++rr) {
    const short* rp = &u.imgc[(y0 + rr) * IMG_RS + colbase];
    bfrag[rr][0] = ld_win(rp);
    bfrag[rr][1] = ld_win(rp + 16);
  }

  short8v a0 = *(const short8v*)aptr;
  short8v a1 = *(const short8v*)(aptr + 512);
#pragma unroll
  for (int dr = 0; dr < RR; ++dr) {
    short8v afrag = a0;
    a0 = a1;
    if (dr < RR - 2) a1 = *(const short8v*)(aptr + (dr + 2) * 512);
#pragma unroll
    for (int rr = 0; rr < 8; ++rr) {
      int slot = (dr + rr) & 7;
      acc[rr * 2 + 0] = __builtin_amdgcn_mfma_f32_16x16x32_bf16(afrag, bfrag[slot][0], acc[rr * 2 + 0], 0, 0, 0);
      acc[rr * 2 + 1] = __builtin_amdgcn_mfma_f32_16x16x32_bf16(afrag, bfrag[slot][1], acc[rr * 2 + 1], 0, 0, 0);
    }
    if (dr < RR - 1) {
      const short* rp = &u.imgc[(y0 + dr + 8) * IMG_RS + colbase];
      int slot = dr & 7;
      bfrag[slot][0] = ld_win(rp);
      bfrag[slot][1] = ld_win(rp + 16);
    }
  }

  __syncthreads();
#pragma unroll
  for (int tt = 0; tt < 16; ++tt) {
    int y = y0 + (tt >> 1), c0 = (tt & 1) << 4;
    int pix = y * 32 + c0 + nl;
#pragma unroll
    for (int r = 0; r < 4; ++r)
      u.lam[(quad * 4 + r) * LAM_RS + pix] = (short)f2bf(acc[tt][r] + lcv[quad * 4 + r]);
  }
  __syncthreads();

  int p0 = t * 4;
  float yacc[4][4];
#pragma unroll
  for (int h = 0; h < 4; ++h)
#pragma unroll
    for (int i = 0; i < 4; ++i) yacc[h][i] = 0.f;
  const float* qb = q_pre + ((size_t)b * 64) * NPIX + p0;
#pragma unroll
  for (int k = 0; k < 16; ++k) {
    uint2 w = *(const uint2*)&u.lam[k * LAM_RS + p0];
    float l0 = bf2f((unsigned short)(w.x & 0xffffu));
    float l1 = bf2f((unsigned short)(w.x >> 16));
    float l2 = bf2f((unsigned short)(w.y & 0xffffu));
    float l3 = bf2f((unsigned short)(w.y >> 16));
#pragma unroll
    for (int h = 0; h < 4; ++h) {
      int o = h * 16 + k;
      float4 qv = *(const float4*)(qb + (size_t)o * NPIX);
      yacc[h][0] = fmaf(fmaf(qv.x, qsc[o], qsh[o]), l0, yacc[h][0]);
      yacc[h][1] = fmaf(fmaf(qv.y, qsc[o], qsh[o]), l1, yacc[h][1]);
      yacc[h][2] = fmaf(fmaf(qv.z, qsc[o], qsh[o]), l2, yacc[h][2]);
      yacc[h][3] = fmaf(fmaf(qv.w, qsc[o], qsh[o]), l3, yacc[h][3]);
    }
  }
  float g1 = 1.0f + gamma[0];
#pragma unroll
  for (int h = 0; h < 4; ++h) {
    float4 r;
    r.x = g1 * yacc[h][0]; r.y = g1 * yacc[h][1];
    r.z = g1 * yacc[h][2]; r.w = g1 * yacc[h][3];
    *(float4*)&out[((size_t)b * 256 + h * 64 + v) * NPIX + p0] = r;
  }
}

extern "C" void kernel_launch(void* const* d_in, const int* in_sizes, int n_in,
                              void* d_out, int out_size, void* d_ws, size_t ws_size,
                              hipStream_t stream) {
  const float* x      = (const float*)d_in[0];
  const float* Wq     = (const float*)d_in[1];
  const float* bn_q_w = (const float*)d_in[2];
  const float* bn_q_b = (const float*)d_in[3];
  const float* Wk     = (const float*)d_in[4];
  const float* Wv     = (const float*)d_in[5];
  const float* bn_v_w = (const float*)d_in[6];
  const float* bn_v_b = (const float*)d_in[7];
  const float* emb    = (const float*)d_in[8];
  const float* gamma  = (const float*)d_in[9];
  float* out = (float*)d_out;

  float* ws    = (float*)d_ws;
  float* q_pre = ws;                                     // B*64*N
  float* k_pre = q_pre + (size_t)BB * 64 * NPIX;         // B*16*N
  float* vn    = k_pre + (size_t)BB * 16 * NPIX;         // B*64*N (raw)
  float* p     = vn    + (size_t)BB * 64 * NPIX;         // B*16*N (fallback only)
  float* raw   = p     + (size_t)BB * 16 * NPIX;         // 256 raw BN sums
  float* lcG   = raw + 256;                              // B*16*64 lambda_c (unnorm)
  float* esum  = lcG + (size_t)BB * 1024;                // B*16 exp sums
  unsigned short* embA = (unsigned short*)(esum + BB * 32);
  unsigned short* wA   = embA + 23 * 16 * 32;            // 144*256 ushorts
  unsigned short* lamG = wA + 144 * 256;                 // B*64*16*N ushorts (64 MB)

  size_t need = ((size_t)(lamG - (unsigned short*)ws)) * 2
              + (size_t)BB * 64 * 16 * NPIX * 2;

  k_prep  <<<dim3(320),       256, 0, stream>>>(emb, embA, Wq, Wk, Wv, wA, raw, lcG, esum);
  k_proj  <<<dim3(16, BB),    256, 0, stream>>>(x, wA, q_pre, k_pre, vn, raw);
  if (ws_size >= need) {
    k_conv<<<dim3(80, BB),    256, 0, stream>>>(vn, k_pre, raw, bn_v_w, bn_v_b, embA, lamG, lcG, esum);
    k_epi2<<<dim3(16, BB, 4), 256, 0, stream>>>(lamG, q_pre, raw, bn_q_w, bn_q_b, lcG, esum, gamma, out);
  } else {
    k_nvsm<<<dim3(32, BB),    256, 0, stream>>>(vn, raw, bn_v_w, bn_v_b, k_pre, p);
    k_fused<<<dim3(64, BB),   256, 0, stream>>>(vn, q_pre, raw, bn_q_w, bn_q_b, p, embA, gamma, out);
  }
}